// Round 5
// baseline (512.962 us; speedup 1.0000x reference)
//
#include <hip/hip_runtime.h>
#include <stdint.h>

#define SEQ   4096
#define NDIM  768
#define HD    64
#define NH    12
#define NBH   24        // 2 * 12
#define MTOT  8192      // 2 * 4096

// GEMM LDS panel row stride in u16: 40 (20 words ≡ 20 mod 32) -> every
// 8-lane phase of a b128 access hits all 32 banks once (stride 32 u16 put
// starts on banks {0,16}: 4-way conflicts, 6.3e7 SQ_LDS_BANK_CONFLICT in R2).
#define LSTR 40
// Attention P panel row stride in u16: rows hold 64 keys (R3/R4 BUG: rows
// were LSTR=40 wide -> keys 40..63 overflowed into the next q-row, bit-
// identical 0.168 absmax both rounds). 72 = 64+8 pad; word stride 36 ≡ 4
// (mod 32): b128 reads tile all 32 banks per 8-lane phase (conflict-free),
// b64 writes are 2 lanes/bank (2-way = free, m136).
#define PSTR 72

typedef short s8v __attribute__((ext_vector_type(8)));     // 8 bf16 (as shorts), 16B
typedef float f4v __attribute__((ext_vector_type(4)));
typedef unsigned short u16;
typedef u16 u16x4 __attribute__((ext_vector_type(4)));

// may_alias types for the P panel (written as packed u32 pairs, read as short8)
typedef uint32_t u32x2a __attribute__((ext_vector_type(2), may_alias));
typedef short    s8va   __attribute__((ext_vector_type(8), may_alias));

// SCALE * log2(e): folded into Q at the QKV epilogue.
#define C1 0.18033688011112042f

__device__ __forceinline__ u16 f2bf(float f) {             // RNE fp32 -> bf16
  union { float f; uint32_t u; } cv; cv.f = f;
  const uint32_t u = cv.u;
  return (u16)((u + 0x7fffu + ((u >> 16) & 1u)) >> 16);
}
__device__ __forceinline__ float ex2(float x) { return __builtin_amdgcn_exp2f(x); }
__device__ __forceinline__ uint32_t fbits(float f) {
  union { float f; uint32_t u; } cv; cv.f = f; return cv.u;
}

// ---------------- fp32 -> bf16 convert (vectorized) ----------------
__global__ __launch_bounds__(256) void cvt_kernel(const float* __restrict__ src,
                                                  u16* __restrict__ dst, int n4) {
  const int i = blockIdx.x * 256 + threadIdx.x;
  if (i >= n4) return;
  const float4 f = ((const float4*)src)[i];
  u16x4 r;
  r[0] = f2bf(f.x); r[1] = f2bf(f.y); r[2] = f2bf(f.z); r[3] = f2bf(f.w);
  ((u16x4*)dst)[i] = r;
}

// ---------------- QKV GEMM: C[8192,2304] = x @ qkv_w^T + b, scattered epilogue ----
// q (scaled by C1), k -> [bh][n][d] ; v -> transposed [bh][d][n]
__global__ __launch_bounds__(256) void gemm_qkv(const u16* __restrict__ A,
    const u16* __restrict__ B, const float* __restrict__ bias,
    u16* __restrict__ qg, u16* __restrict__ kg, u16* __restrict__ vtg) {
  __shared__ __align__(16) u16 at[128 * LSTR];
  __shared__ __align__(16) u16 bt[128 * LSTR];
  const int tid  = threadIdx.x;
  const int lane = tid & 63;
  const int w    = tid >> 6;
  const int quad = lane >> 4;
  const int col  = lane & 15;
  const int m0 = blockIdx.y * 128;
  const int n0 = blockIdx.x * 128;
  const int srow = tid >> 2;
  const int sch  = (tid & 3) * 8;
  const int wm = (w >> 1) * 64;
  const int wn = (w & 1) * 64;

  const f4v fz = {0.f, 0.f, 0.f, 0.f};
  f4v acc[4][4];
#pragma unroll
  for (int i = 0; i < 4; i++)
#pragma unroll
    for (int j = 0; j < 4; j++) acc[i][j] = fz;

  const u16* ap0 = A + (size_t)(m0 + srow) * NDIM + sch;
  const u16* ap1 = A + (size_t)(m0 + 64 + srow) * NDIM + sch;
  const u16* bp0 = B + (size_t)(n0 + srow) * NDIM + sch;
  const u16* bp1 = B + (size_t)(n0 + 64 + srow) * NDIM + sch;

  for (int k0 = 0; k0 < NDIM; k0 += 32) {
    const s8v va0 = *(const s8v*)(ap0 + k0);
    const s8v va1 = *(const s8v*)(ap1 + k0);
    const s8v vb0 = *(const s8v*)(bp0 + k0);
    const s8v vb1 = *(const s8v*)(bp1 + k0);
    __syncthreads();
    *(s8v*)(at + srow * LSTR + sch) = va0;
    *(s8v*)(at + (64 + srow) * LSTR + sch) = va1;
    *(s8v*)(bt + srow * LSTR + sch) = vb0;
    *(s8v*)(bt + (64 + srow) * LSTR + sch) = vb1;
    __syncthreads();
    s8v af[4], bf[4];
#pragma unroll
    for (int i = 0; i < 4; i++)
      af[i] = *(const s8v*)(at + (wm + i * 16 + col) * LSTR + quad * 8);
#pragma unroll
    for (int j = 0; j < 4; j++)
      bf[j] = *(const s8v*)(bt + (wn + j * 16 + col) * LSTR + quad * 8);
#pragma unroll
    for (int i = 0; i < 4; i++)
#pragma unroll
      for (int j = 0; j < 4; j++)
        acc[i][j] = __builtin_amdgcn_mfma_f32_16x16x32_bf16(af[i], bf[j], acc[i][j], 0, 0, 0);
  }

  const int wmg = m0 + wm;
  const int wng = n0 + wn;
  const int s = n0 / NDIM;   // 0=q 1=k 2=v, block-uniform (768 = 6*128)
#pragma unroll
  for (int j = 0; j < 4; j++) {
    const int c = wng + j * 16 + col;
    const float bv = bias[c];
    const int r = c - s * NDIM;
    const int h = r >> 6;
    const int d = r & 63;
#pragma unroll
    for (int i = 0; i < 4; i++) {
      const int mb = wmg + i * 16 + quad * 4;   // 4 consecutive rows (regs)
      const int bb = mb >> 12;
      const int n  = mb & 4095;
      const size_t hb = (size_t)(bb * NH + h);
      const f4v v = acc[i][j];
      if (s == 2) {
        u16x4 pk;
#pragma unroll
        for (int rg = 0; rg < 4; rg++) pk[rg] = f2bf(v[rg] + bv);
        *(u16x4*)(vtg + (hb * HD + d) * SEQ + n) = pk;   // transposed store
      } else if (s == 0) {
#pragma unroll
        for (int rg = 0; rg < 4; rg++)
          qg[(hb * SEQ + (size_t)(n + rg)) * HD + d] = f2bf((v[rg] + bv) * C1);
      } else {
#pragma unroll
        for (int rg = 0; rg < 4; rg++)
          kg[(hb * SEQ + (size_t)(n + rg)) * HD + d] = f2bf(v[rg] + bv);
      }
    }
  }
}

// ---------------- flash attention (register-fragment, barrier-free) ----------------
// All MFMA A/B fragments are 16B-contiguous in the global layouts:
//   K A-frag  = K[kb+kt*16+col][s*32+quad*8 ..+7]      (kg  [bh][n][d])
//   Vt A-frag = Vt[dt*16+col][kb+s*32+quad*8 ..+7]     (vtg [bh][d][n])
//   Q B-frag  = Q[q0+wq+qt*16+col][s*32+quad*8 ..+7]   (qg  [bh][n][d], regs)
// so K/V/Q never touch LDS. Only P round-trips through a wave-PRIVATE padded
// LDS panel (C-layout -> B-layout transform) => no __syncthreads anywhere.
__global__ __launch_bounds__(256) void attn_kernel(const u16* __restrict__ qg,
    const u16* __restrict__ kg, const u16* __restrict__ vtg, u16* __restrict__ og) {
  __shared__ __align__(16) u16 pls[128 * PSTR];   // [q row][64 keys + 8 pad]

  const int tid  = threadIdx.x;
  const int lane = tid & 63;
  const int w    = tid >> 6;
  const int quad = lane >> 4;
  const int col  = lane & 15;
  // XCD swizzle: bh = blk % 24 -> all q-tiles of one (b,h) land on the same
  // XCD (blocks bh+24j: 24j % 8 == 0), so each XCD L2 holds 3 heads' K/V
  // (3 MB < 4 MB) for the whole kernel.
  const int blk = blockIdx.x;
  const int bh  = blk % NBH;
  const int q0  = (blk / NBH) * 128;
  const size_t gbase = (size_t)bh * (SEQ * HD);
  const int wq = w * 32;           // this wave's q-column base

  // Q fragments in registers, once per block
  s8v qf[2][2];
#pragma unroll
  for (int s = 0; s < 2; s++)
#pragma unroll
    for (int qt = 0; qt < 2; qt++)
      qf[s][qt] = *(const s8v*)(qg + gbase +
          (size_t)(q0 + wq + qt * 16 + col) * HD + s * 32 + quad * 8);

  const f4v fz = {0.f, 0.f, 0.f, 0.f};
  f4v l4[2] = {fz, fz};
  f4v o[4][2];
#pragma unroll
  for (int dt = 0; dt < 4; dt++)
#pragma unroll
    for (int qt = 0; qt < 2; qt++) o[dt][qt] = fz;

  // lane-constant base pointers; per-iter index advances uniformly
  const u16* kbase = kg  + gbase + (size_t)col * HD  + quad * 8;
  const u16* vbase = vtg + gbase + (size_t)col * SEQ + quad * 8;
  u16* const prow = pls + (wq + col) * PSTR;       // + qt*16*PSTR

  for (int kb = 0; kb < SEQ; kb += 64) {
    // K fragments straight from global (L1/L2-resident)
    s8v kf[2][4];
#pragma unroll
    for (int s = 0; s < 2; s++)
#pragma unroll
      for (int kt = 0; kt < 4; kt++)
        kf[s][kt] = *(const s8v*)(kbase + (size_t)(kb + kt * 16) * HD + s * 32);

    // St = K @ Q^T (C-layout: row=key, col=q)
    f4v st[4][2];
#pragma unroll
    for (int kt = 0; kt < 4; kt++)
#pragma unroll
      for (int qt = 0; qt < 2; qt++) st[kt][qt] = fz;
#pragma unroll
    for (int s = 0; s < 2; s++)
#pragma unroll
      for (int kt = 0; kt < 4; kt++)
#pragma unroll
        for (int qt = 0; qt < 2; qt++)
          st[kt][qt] = __builtin_amdgcn_mfma_f32_16x16x32_bf16(kf[s][kt], qf[s][qt], st[kt][qt], 0, 0, 0);

    // V fragments issued now; latency hides under softmax VALU
    s8v vf[2][4];
#pragma unroll
    for (int s = 0; s < 2; s++)
#pragma unroll
      for (int dt = 0; dt < 4; dt++)
        vf[s][dt] = *(const s8v*)(vbase + (size_t)(dt * 16) * SEQ + kb + s * 32);

    // p = exp2(st); per-lane l; pack bf16 (round-half-up + v_perm), b64 write
    // into the wave-private padded P panel: row = q, offset = key (0..63).
#pragma unroll
    for (int qt = 0; qt < 2; qt++) {
      u16* const pq = prow + qt * 16 * PSTR;
#pragma unroll
      for (int kt = 0; kt < 4; kt++) {
        f4v p;
#pragma unroll
        for (int rg = 0; rg < 4; rg++) p[rg] = ex2(st[kt][qt][rg]);
        l4[qt] += p;
        const uint32_t u0 = fbits(p[0]) + 0x8000u;
        const uint32_t u1 = fbits(p[1]) + 0x8000u;
        const uint32_t u2 = fbits(p[2]) + 0x8000u;
        const uint32_t u3 = fbits(p[3]) + 0x8000u;
        u32x2a wv;
        wv.x = __builtin_amdgcn_perm(u1, u0, 0x07060302u);
        wv.y = __builtin_amdgcn_perm(u3, u2, 0x07060302u);
        *(u32x2a*)(pq + kt * 16 + quad * 4) = wv;
      }
    }
    // compiler memory fence: P writes precede the B-frag reads below
    asm volatile("" ::: "memory");

    // O' += Vt @ Pt (B-frag of Pt read back from the private panel)
#pragma unroll
    for (int s = 0; s < 2; s++) {
      s8va bp[2];
#pragma unroll
      for (int qt = 0; qt < 2; qt++)
        bp[qt] = *(const s8va*)(prow + qt * 16 * PSTR + s * 32 + quad * 8);
#pragma unroll
      for (int dt = 0; dt < 4; dt++)
#pragma unroll
        for (int qt = 0; qt < 2; qt++)
          o[dt][qt] = __builtin_amdgcn_mfma_f32_16x16x32_bf16(vf[s][dt], (s8v)bp[qt], o[dt][qt], 0, 0, 0);
    }
    // fence: next iter's P writes (same addrs) must not hoist above these reads
    asm volatile("" ::: "memory");
  }

  // epilogue: reduce l across quads, O'[d][q]/l -> attn_out[b*4096+q][h*64+d]
  const int b = bh / NH;
  const int h = bh % NH;
#pragma unroll
  for (int qt = 0; qt < 2; qt++) {
    float l = l4[qt][0] + l4[qt][1] + l4[qt][2] + l4[qt][3];
    l += __shfl_xor(l, 16);
    l += __shfl_xor(l, 32);
    const float inv = 1.0f / l;
    const int qi = q0 + wq + qt * 16 + col;
    u16* rowp = og + (size_t)(b * SEQ + qi) * NDIM + h * HD;
#pragma unroll
    for (int dt = 0; dt < 4; dt++) {
      u16x4 pk;
#pragma unroll
      for (int rg = 0; rg < 4; rg++) pk[rg] = f2bf(o[dt][qt][rg] * inv);
      *(u16x4*)(rowp + dt * 16 + quad * 4) = pk;
    }
  }
}

// ---------------- proj GEMM: out[8192,768] = attn @ proj_w^T + b (fp32 out) ----
__global__ __launch_bounds__(256) void gemm_proj(const u16* __restrict__ A,
    const u16* __restrict__ B, const float* __restrict__ bias, float* __restrict__ out) {
  __shared__ __align__(16) u16 at[128 * LSTR];
  __shared__ __align__(16) u16 bt[128 * LSTR];
  const int tid  = threadIdx.x;
  const int lane = tid & 63;
  const int w    = tid >> 6;
  const int quad = lane >> 4;
  const int col  = lane & 15;
  const int m0 = blockIdx.y * 128;
  const int n0 = blockIdx.x * 128;
  const int srow = tid >> 2;
  const int sch  = (tid & 3) * 8;
  const int wm = (w >> 1) * 64;
  const int wn = (w & 1) * 64;

  const f4v fz = {0.f, 0.f, 0.f, 0.f};
  f4v acc[4][4];
#pragma unroll
  for (int i = 0; i < 4; i++)
#pragma unroll
    for (int j = 0; j < 4; j++) acc[i][j] = fz;

  const u16* ap0 = A + (size_t)(m0 + srow) * NDIM + sch;
  const u16* ap1 = A + (size_t)(m0 + 64 + srow) * NDIM + sch;
  const u16* bp0 = B + (size_t)(n0 + srow) * NDIM + sch;
  const u16* bp1 = B + (size_t)(n0 + 64 + srow) * NDIM + sch;

  for (int k0 = 0; k0 < NDIM; k0 += 32) {
    const s8v va0 = *(const s8v*)(ap0 + k0);
    const s8v va1 = *(const s8v*)(ap1 + k0);
    const s8v vb0 = *(const s8v*)(bp0 + k0);
    const s8v vb1 = *(const s8v*)(bp1 + k0);
    __syncthreads();
    *(s8v*)(at + srow * LSTR + sch) = va0;
    *(s8v*)(at + (64 + srow) * LSTR + sch) = va1;
    *(s8v*)(bt + srow * LSTR + sch) = vb0;
    *(s8v*)(bt + (64 + srow) * LSTR + sch) = vb1;
    __syncthreads();
    s8v af[4], bf[4];
#pragma unroll
    for (int i = 0; i < 4; i++)
      af[i] = *(const s8v*)(at + (wm + i * 16 + col) * LSTR + quad * 8);
#pragma unroll
    for (int j = 0; j < 4; j++)
      bf[j] = *(const s8v*)(bt + (wn + j * 16 + col) * LSTR + quad * 8);
#pragma unroll
    for (int i = 0; i < 4; i++)
#pragma unroll
      for (int j = 0; j < 4; j++)
        acc[i][j] = __builtin_amdgcn_mfma_f32_16x16x32_bf16(af[i], bf[j], acc[i][j], 0, 0, 0);
  }

  const int wmg = m0 + wm;
  const int wng = n0 + wn;
#pragma unroll
  for (int j = 0; j < 4; j++) {
    const int c = wng + j * 16 + col;
    const float bv = bias[c];
#pragma unroll
    for (int i = 0; i < 4; i++) {
#pragma unroll
      for (int rg = 0; rg < 4; rg++)
        out[(size_t)(wmg + i * 16 + quad * 4 + rg) * NDIM + c] = acc[i][j][rg] + bv;
    }
  }
}

// ---------------- launch ----------------
extern "C" void kernel_launch(void* const* d_in, const int* in_sizes, int n_in,
                              void* d_out, int out_size, void* d_ws, size_t ws_size,
                              hipStream_t stream) {
  const float* x      = (const float*)d_in[0];
  const float* qkv_w  = (const float*)d_in[1];
  const float* qkv_b  = (const float*)d_in[2];
  const float* proj_w = (const float*)d_in[3];
  const float* proj_b = (const float*)d_in[4];
  float* out = (float*)d_out;

  u16* ws   = (u16*)d_ws;
  u16* x_bf = ws;                              // 8192*768
  u16* wq   = x_bf + (size_t)MTOT * NDIM;      // 2304*768
  u16* wp   = wq + (size_t)3 * NDIM * NDIM;    // 768*768
  u16* q_bf = wp + (size_t)NDIM * NDIM;        // 24*4096*64 each
  u16* k_bf = q_bf + (size_t)NBH * SEQ * HD;
  u16* vt   = k_bf + (size_t)NBH * SEQ * HD;
  u16* a_bf = vt + (size_t)NBH * SEQ * HD;     // 8192*768

  const int nx = MTOT * NDIM / 4, nw1 = 3 * NDIM * NDIM / 4, nw2 = NDIM * NDIM / 4;
  cvt_kernel<<<(nx + 255) / 256, 256, 0, stream>>>(x, x_bf, nx);
  cvt_kernel<<<(nw1 + 255) / 256, 256, 0, stream>>>(qkv_w, wq, nw1);
  cvt_kernel<<<(nw2 + 255) / 256, 256, 0, stream>>>(proj_w, wp, nw2);

  gemm_qkv<<<dim3(18, 64), 256, 0, stream>>>(x_bf, wq, qkv_b, q_bf, k_bf, vt);
  attn_kernel<<<768, 256, 0, stream>>>(q_bf, k_bf, vt, a_bf);
  gemm_proj<<<dim3(6, 64), 256, 0, stream>>>(a_bf, wp, proj_b, out);
}

// Round 6
// 310.416 us; speedup vs baseline: 1.6525x; 1.6525x over previous
//
#include <hip/hip_runtime.h>
#include <stdint.h>

#define SEQ   4096
#define NDIM  768
#define HD    64
#define NH    12
#define NBH   24        // 2 * 12
#define MTOT  8192      // 2 * 4096

// GEMM/KV LDS panel row stride in u16: 40 (20 words ≡ 20 mod 32) -> every
// 8-lane phase of a b128 fragment read hits all 32 banks exactly once
// (verified: lane l reads words 20l..20l+3 -> banks {0,20,8,28,16,4,24,12}x4,
// full cover). Stride 32 was 4-way conflicted: 6.3e7 SQ_LDS_BANK_CONFLICT
// in R2 ~= 50% of kernel cycles.
#define LSTR 40
// Attention P panel row stride in u16: 64 keys + 8 pad (R3/R4 bug was rows
// of 40 -> keys 40..63 overflowed into the next q-row). Word stride 36 ≡ 4
// (mod 32): b128 reads conflict-free, b64 writes 2-way (free, m136).
#define PSTR 72

typedef short s8v __attribute__((ext_vector_type(8)));     // 8 bf16 (as shorts), 16B
typedef float f4v __attribute__((ext_vector_type(4)));
typedef unsigned short u16;
typedef u16 u16x4 __attribute__((ext_vector_type(4)));

// may_alias types for the P panel (written as packed u32 pairs, read as short8)
typedef uint32_t u32x2a __attribute__((ext_vector_type(2), may_alias));
typedef short    s8va   __attribute__((ext_vector_type(8), may_alias));

// SCALE * log2(e): folded into Q at the QKV epilogue.
#define C1 0.18033688011112042f

__device__ __forceinline__ u16 f2bf(float f) {             // RNE fp32 -> bf16
  union { float f; uint32_t u; } cv; cv.f = f;
  const uint32_t u = cv.u;
  return (u16)((u + 0x7fffu + ((u >> 16) & 1u)) >> 16);
}
__device__ __forceinline__ float ex2(float x) { return __builtin_amdgcn_exp2f(x); }
__device__ __forceinline__ uint32_t fbits(float f) {
  union { float f; uint32_t u; } cv; cv.f = f; return cv.u;
}

// ---------------- fp32 -> bf16 convert (vectorized) ----------------
__global__ __launch_bounds__(256) void cvt_kernel(const float* __restrict__ src,
                                                  u16* __restrict__ dst, int n4) {
  const int i = blockIdx.x * 256 + threadIdx.x;
  if (i >= n4) return;
  const float4 f = ((const float4*)src)[i];
  u16x4 r;
  r[0] = f2bf(f.x); r[1] = f2bf(f.y); r[2] = f2bf(f.z); r[3] = f2bf(f.w);
  ((u16x4*)dst)[i] = r;
}

// ---------------- QKV GEMM: C[8192,2304] = x @ qkv_w^T + b, scattered epilogue ----
// q (scaled by C1), k -> [bh][n][d] ; v -> transposed [bh][d][n]
__global__ __launch_bounds__(256) void gemm_qkv(const u16* __restrict__ A,
    const u16* __restrict__ B, const float* __restrict__ bias,
    u16* __restrict__ qg, u16* __restrict__ kg, u16* __restrict__ vtg) {
  __shared__ __align__(16) u16 at[128 * LSTR];
  __shared__ __align__(16) u16 bt[128 * LSTR];
  const int tid  = threadIdx.x;
  const int lane = tid & 63;
  const int w    = tid >> 6;
  const int quad = lane >> 4;
  const int col  = lane & 15;
  const int m0 = blockIdx.y * 128;
  const int n0 = blockIdx.x * 128;
  const int srow = tid >> 2;
  const int sch  = (tid & 3) * 8;
  const int wm = (w >> 1) * 64;
  const int wn = (w & 1) * 64;

  const f4v fz = {0.f, 0.f, 0.f, 0.f};
  f4v acc[4][4];
#pragma unroll
  for (int i = 0; i < 4; i++)
#pragma unroll
    for (int j = 0; j < 4; j++) acc[i][j] = fz;

  const u16* ap0 = A + (size_t)(m0 + srow) * NDIM + sch;
  const u16* ap1 = A + (size_t)(m0 + 64 + srow) * NDIM + sch;
  const u16* bp0 = B + (size_t)(n0 + srow) * NDIM + sch;
  const u16* bp1 = B + (size_t)(n0 + 64 + srow) * NDIM + sch;

  for (int k0 = 0; k0 < NDIM; k0 += 32) {
    const s8v va0 = *(const s8v*)(ap0 + k0);
    const s8v va1 = *(const s8v*)(ap1 + k0);
    const s8v vb0 = *(const s8v*)(bp0 + k0);
    const s8v vb1 = *(const s8v*)(bp1 + k0);
    __syncthreads();
    *(s8v*)(at + srow * LSTR + sch) = va0;
    *(s8v*)(at + (64 + srow) * LSTR + sch) = va1;
    *(s8v*)(bt + srow * LSTR + sch) = vb0;
    *(s8v*)(bt + (64 + srow) * LSTR + sch) = vb1;
    __syncthreads();
    s8v af[4], bf[4];
#pragma unroll
    for (int i = 0; i < 4; i++)
      af[i] = *(const s8v*)(at + (wm + i * 16 + col) * LSTR + quad * 8);
#pragma unroll
    for (int j = 0; j < 4; j++)
      bf[j] = *(const s8v*)(bt + (wn + j * 16 + col) * LSTR + quad * 8);
#pragma unroll
    for (int i = 0; i < 4; i++)
#pragma unroll
      for (int j = 0; j < 4; j++)
        acc[i][j] = __builtin_amdgcn_mfma_f32_16x16x32_bf16(af[i], bf[j], acc[i][j], 0, 0, 0);
  }

  const int wmg = m0 + wm;
  const int wng = n0 + wn;
  const int s = n0 / NDIM;   // 0=q 1=k 2=v, block-uniform (768 = 6*128)
#pragma unroll
  for (int j = 0; j < 4; j++) {
    const int c = wng + j * 16 + col;
    const float bv = bias[c];
    const int r = c - s * NDIM;
    const int h = r >> 6;
    const int d = r & 63;
#pragma unroll
    for (int i = 0; i < 4; i++) {
      const int mb = wmg + i * 16 + quad * 4;   // 4 consecutive rows (regs)
      const int bb = mb >> 12;
      const int n  = mb & 4095;
      const size_t hb = (size_t)(bb * NH + h);
      const f4v v = acc[i][j];
      if (s == 2) {
        u16x4 pk;
#pragma unroll
        for (int rg = 0; rg < 4; rg++) pk[rg] = f2bf(v[rg] + bv);
        *(u16x4*)(vtg + (hb * HD + d) * SEQ + n) = pk;   // transposed store
      } else if (s == 0) {
#pragma unroll
        for (int rg = 0; rg < 4; rg++)
          qg[(hb * SEQ + (size_t)(n + rg)) * HD + d] = f2bf((v[rg] + bv) * C1);
      } else {
#pragma unroll
        for (int rg = 0; rg < 4; rg++)
          kg[(hb * SEQ + (size_t)(n + rg)) * HD + d] = f2bf(v[rg] + bv);
      }
    }
  }
}

// ---------------- flash attention (LDS-staged K/V, conflict-free panels) ----------------
// K/V staged per block with coalesced 16B loads (4-wave sharing; R5's
// direct-from-global frags were latency-bound at 364us: MfmaUtil 11.6%,
// VALUBusy 19%, all pipes idle). Q frags live in registers (R5-verified).
// P round-trips a wave-PRIVATE stride-72 panel (no barrier needed for it).
__global__ __launch_bounds__(256) void attn_kernel(const u16* __restrict__ qg,
    const u16* __restrict__ kg, const u16* __restrict__ vtg, u16* __restrict__ og) {
  __shared__ __align__(16) u16 kls[2 * 64 * LSTR];  // [d-half][key][40]
  __shared__ __align__(16) u16 vls[2 * 64 * LSTR];  // [key-half][d row][40]
  __shared__ __align__(16) u16 pls[128 * PSTR];     // [q row][64 keys + 8 pad]

  const int tid  = threadIdx.x;
  const int lane = tid & 63;
  const int w    = tid >> 6;
  const int quad = lane >> 4;
  const int col  = lane & 15;
  // XCD swizzle: bh = blk % 24 -> all q-tiles of one (b,h) land on the same
  // XCD (blocks bh+24j: 24j % 8 == 0) -> K/V L2-resident per XCD.
  const int blk = blockIdx.x;
  const int bh  = blk % NBH;
  const int q0  = (blk / NBH) * 128;
  const size_t gbase = (size_t)bh * (SEQ * HD);
  const int wq = w * 32;           // this wave's q-column base

  // Q fragments in registers, once per block (R5-verified mapping)
  s8v qf[2][2];
#pragma unroll
  for (int s = 0; s < 2; s++)
#pragma unroll
    for (int qt = 0; qt < 2; qt++)
      qf[s][qt] = *(const s8v*)(qg + gbase +
          (size_t)(q0 + wq + qt * 16 + col) * HD + s * 32 + quad * 8);

  const f4v fz = {0.f, 0.f, 0.f, 0.f};
  f4v l4[2] = {fz, fz};
  f4v o[4][2];
#pragma unroll
  for (int dt = 0; dt < 4; dt++)
#pragma unroll
    for (int qt = 0; qt < 2; qt++) o[dt][qt] = fz;

  const int srow = tid >> 2;
  const int sch  = (tid & 3) * 8;
  const u16* kp = kg  + gbase + (size_t)srow * HD  + sch;
  const u16* vp = vtg + gbase + (size_t)srow * SEQ + sch;
  u16* const prow = pls + (wq + col) * PSTR;       // + qt*16*PSTR

  // prefetch iter 0 (coalesced 16B/lane)
  s8v kr0 = *(const s8v*)(kp);
  s8v kr1 = *(const s8v*)(kp + 32);
  s8v vr0 = *(const s8v*)(vp);
  s8v vr1 = *(const s8v*)(vp + 32);

  for (int kb = 0; kb < SEQ; kb += 64) {
    __syncthreads();
    *(s8v*)(kls + srow * LSTR + sch) = kr0;
    *(s8v*)(kls + 64 * LSTR + srow * LSTR + sch) = kr1;
    *(s8v*)(vls + srow * LSTR + sch) = vr0;
    *(s8v*)(vls + 64 * LSTR + srow * LSTR + sch) = vr1;
    __syncthreads();

    // prefetch next K/V tile; latency hides under this iter's compute
    if (kb + 64 < SEQ) {
      kr0 = *(const s8v*)(kp + (size_t)(kb + 64) * HD);
      kr1 = *(const s8v*)(kp + (size_t)(kb + 64) * HD + 32);
      vr0 = *(const s8v*)(vp + kb + 64);
      vr1 = *(const s8v*)(vp + kb + 96);
    }

    // St = K @ Q^T (C-layout: row=key, col=q), 2 K-steps over d
    f4v st[4][2];
#pragma unroll
    for (int kt = 0; kt < 4; kt++)
#pragma unroll
      for (int qt = 0; qt < 2; qt++) st[kt][qt] = fz;
#pragma unroll
    for (int s = 0; s < 2; s++) {
#pragma unroll
      for (int kt = 0; kt < 4; kt++) {
        const s8v ak = *(const s8v*)(kls + s * (64 * LSTR) + (kt * 16 + col) * LSTR + quad * 8);
#pragma unroll
        for (int qt = 0; qt < 2; qt++)
          st[kt][qt] = __builtin_amdgcn_mfma_f32_16x16x32_bf16(ak, qf[s][qt], st[kt][qt], 0, 0, 0);
      }
    }

    // p = exp2(st); per-lane l; pack bf16 (round-half-up + v_perm), b64 write
    // into the wave-private padded P panel: row = q, offset = key (0..63).
#pragma unroll
    for (int qt = 0; qt < 2; qt++) {
      u16* const pq = prow + qt * 16 * PSTR;
#pragma unroll
      for (int kt = 0; kt < 4; kt++) {
        f4v p;
#pragma unroll
        for (int rg = 0; rg < 4; rg++) p[rg] = ex2(st[kt][qt][rg]);
        l4[qt] += p;
        const uint32_t u0 = fbits(p[0]) + 0x8000u;
        const uint32_t u1 = fbits(p[1]) + 0x8000u;
        const uint32_t u2 = fbits(p[2]) + 0x8000u;
        const uint32_t u3 = fbits(p[3]) + 0x8000u;
        u32x2a wv;
        wv.x = __builtin_amdgcn_perm(u1, u0, 0x07060302u);
        wv.y = __builtin_amdgcn_perm(u3, u2, 0x07060302u);
        *(u32x2a*)(pq + kt * 16 + quad * 4) = wv;
      }
    }
    // compiler memory fence: P writes precede the B-frag reads below
    asm volatile("" ::: "memory");

    // O' += Vt @ Pt, 2 K-steps over keys
#pragma unroll
    for (int s = 0; s < 2; s++) {
      s8va bp[2];
#pragma unroll
      for (int qt = 0; qt < 2; qt++)
        bp[qt] = *(const s8va*)(prow + qt * 16 * PSTR + s * 32 + quad * 8);
#pragma unroll
      for (int dt = 0; dt < 4; dt++) {
        const s8v av = *(const s8v*)(vls + s * (64 * LSTR) + (dt * 16 + col) * LSTR + quad * 8);
#pragma unroll
        for (int qt = 0; qt < 2; qt++)
          o[dt][qt] = __builtin_amdgcn_mfma_f32_16x16x32_bf16(av, (s8v)bp[qt], o[dt][qt], 0, 0, 0);
      }
    }
    // fence: next iter's P writes (same addrs) must not hoist above these reads
    asm volatile("" ::: "memory");
  }

  // epilogue: reduce l across quads, O'[d][q]/l -> attn_out[b*4096+q][h*64+d]
  const int b = bh / NH;
  const int h = bh % NH;
#pragma unroll
  for (int qt = 0; qt < 2; qt++) {
    float l = l4[qt][0] + l4[qt][1] + l4[qt][2] + l4[qt][3];
    l += __shfl_xor(l, 16);
    l += __shfl_xor(l, 32);
    const float inv = 1.0f / l;
    const int qi = q0 + wq + qt * 16 + col;
    u16* rowp = og + (size_t)(b * SEQ + qi) * NDIM + h * HD;
#pragma unroll
    for (int dt = 0; dt < 4; dt++) {
      u16x4 pk;
#pragma unroll
      for (int rg = 0; rg < 4; rg++) pk[rg] = f2bf(o[dt][qt][rg] * inv);
      *(u16x4*)(rowp + dt * 16 + quad * 4) = pk;
    }
  }
}

// ---------------- proj GEMM: out[8192,768] = attn @ proj_w^T + b (fp32 out) ----
__global__ __launch_bounds__(256) void gemm_proj(const u16* __restrict__ A,
    const u16* __restrict__ B, const float* __restrict__ bias, float* __restrict__ out) {
  __shared__ __align__(16) u16 at[128 * LSTR];
  __shared__ __align__(16) u16 bt[128 * LSTR];
  const int tid  = threadIdx.x;
  const int lane = tid & 63;
  const int w    = tid >> 6;
  const int quad = lane >> 4;
  const int col  = lane & 15;
  const int m0 = blockIdx.y * 128;
  const int n0 = blockIdx.x * 128;
  const int srow = tid >> 2;
  const int sch  = (tid & 3) * 8;
  const int wm = (w >> 1) * 64;
  const int wn = (w & 1) * 64;

  const f4v fz = {0.f, 0.f, 0.f, 0.f};
  f4v acc[4][4];
#pragma unroll
  for (int i = 0; i < 4; i++)
#pragma unroll
    for (int j = 0; j < 4; j++) acc[i][j] = fz;

  const u16* ap0 = A + (size_t)(m0 + srow) * NDIM + sch;
  const u16* ap1 = A + (size_t)(m0 + 64 + srow) * NDIM + sch;
  const u16* bp0 = B + (size_t)(n0 + srow) * NDIM + sch;
  const u16* bp1 = B + (size_t)(n0 + 64 + srow) * NDIM + sch;

  for (int k0 = 0; k0 < NDIM; k0 += 32) {
    const s8v va0 = *(const s8v*)(ap0 + k0);
    const s8v va1 = *(const s8v*)(ap1 + k0);
    const s8v vb0 = *(const s8v*)(bp0 + k0);
    const s8v vb1 = *(const s8v*)(bp1 + k0);
    __syncthreads();
    *(s8v*)(at + srow * LSTR + sch) = va0;
    *(s8v*)(at + (64 + srow) * LSTR + sch) = va1;
    *(s8v*)(bt + srow * LSTR + sch) = vb0;
    *(s8v*)(bt + (64 + srow) * LSTR + sch) = vb1;
    __syncthreads();
    s8v af[4], bf[4];
#pragma unroll
    for (int i = 0; i < 4; i++)
      af[i] = *(const s8v*)(at + (wm + i * 16 + col) * LSTR + quad * 8);
#pragma unroll
    for (int j = 0; j < 4; j++)
      bf[j] = *(const s8v*)(bt + (wn + j * 16 + col) * LSTR + quad * 8);
#pragma unroll
    for (int i = 0; i < 4; i++)
#pragma unroll
      for (int j = 0; j < 4; j++)
        acc[i][j] = __builtin_amdgcn_mfma_f32_16x16x32_bf16(af[i], bf[j], acc[i][j], 0, 0, 0);
  }

  const int wmg = m0 + wm;
  const int wng = n0 + wn;
#pragma unroll
  for (int j = 0; j < 4; j++) {
    const int c = wng + j * 16 + col;
    const float bv = bias[c];
#pragma unroll
    for (int i = 0; i < 4; i++) {
#pragma unroll
      for (int rg = 0; rg < 4; rg++)
        out[(size_t)(wmg + i * 16 + quad * 4 + rg) * NDIM + c] = acc[i][j][rg] + bv;
    }
  }
}

// ---------------- launch ----------------
extern "C" void kernel_launch(void* const* d_in, const int* in_sizes, int n_in,
                              void* d_out, int out_size, void* d_ws, size_t ws_size,
                              hipStream_t stream) {
  const float* x      = (const float*)d_in[0];
  const float* qkv_w  = (const float*)d_in[1];
  const float* qkv_b  = (const float*)d_in[2];
  const float* proj_w = (const float*)d_in[3];
  const float* proj_b = (const float*)d_in[4];
  float* out = (float*)d_out;

  u16* ws   = (u16*)d_ws;
  u16* x_bf = ws;                              // 8192*768
  u16* wq   = x_bf + (size_t)MTOT * NDIM;      // 2304*768
  u16* wp   = wq + (size_t)3 * NDIM * NDIM;    // 768*768
  u16* q_bf = wp + (size_t)NDIM * NDIM;        // 24*4096*64 each
  u16* k_bf = q_bf + (size_t)NBH * SEQ * HD;
  u16* vt   = k_bf + (size_t)NBH * SEQ * HD;
  u16* a_bf = vt + (size_t)NBH * SEQ * HD;     // 8192*768

  const int nx = MTOT * NDIM / 4, nw1 = 3 * NDIM * NDIM / 4, nw2 = NDIM * NDIM / 4;
  cvt_kernel<<<(nx + 255) / 256, 256, 0, stream>>>(x, x_bf, nx);
  cvt_kernel<<<(nw1 + 255) / 256, 256, 0, stream>>>(qkv_w, wq, nw1);
  cvt_kernel<<<(nw2 + 255) / 256, 256, 0, stream>>>(proj_w, wp, nw2);

  gemm_qkv<<<dim3(18, 64), 256, 0, stream>>>(x_bf, wq, qkv_b, q_bf, k_bf, vt);
  attn_kernel<<<768, 256, 0, stream>>>(q_bf, k_bf, vt, a_bf);
  gemm_proj<<<dim3(6, 64), 256, 0, stream>>>(a_bf, wp, proj_b, out);
}

// Round 7
// 304.223 us; speedup vs baseline: 1.6861x; 1.0204x over previous
//
#include <hip/hip_runtime.h>
#include <stdint.h>

#define SEQ   4096
#define NDIM  768
#define HD    64
#define NH    12
#define NBH   24        // 2 * 12
#define MTOT  8192      // 2 * 4096

// GEMM LDS panel row stride in u16 (32-k chunks per row): 40.
#define LSTR 40
// Attention panel row stride in u16: rows of 64 elems + 8 pad. Word stride
// 36 ≡ 4 (mod 32). With 8-lanes-per-row staging (row=tid>>3, chunk=(tid&7)*8)
// write phases are words 4i..4i+3 per lane -> perfect bank tiling; frag reads
// (row*36 + s*16 + quad*4) full-cover all 32 banks per 8-lane phase. R6's
// 4-lanes-per-row stride-40 staging had lane7/lane0 collisions -> 2.83e7
// SQ_LDS_BANK_CONFLICT ~= 28% of kernel cycles on a 72%-busy LDS pipe.
#define PSTR 72

typedef short s8v __attribute__((ext_vector_type(8)));     // 8 bf16 (as shorts), 16B
typedef float f4v __attribute__((ext_vector_type(4)));
typedef unsigned short u16;
typedef u16 u16x4 __attribute__((ext_vector_type(4)));

// may_alias types for the P panel (written as packed u32 pairs, read as short8)
typedef uint32_t u32x2a __attribute__((ext_vector_type(2), may_alias));
typedef short    s8va   __attribute__((ext_vector_type(8), may_alias));

// SCALE * log2(e): folded into Q at the QKV epilogue.
#define C1 0.18033688011112042f

__device__ __forceinline__ u16 f2bf(float f) {             // RNE fp32 -> bf16
  union { float f; uint32_t u; } cv; cv.f = f;
  const uint32_t u = cv.u;
  return (u16)((u + 0x7fffu + ((u >> 16) & 1u)) >> 16);
}
__device__ __forceinline__ float ex2(float x) { return __builtin_amdgcn_exp2f(x); }
__device__ __forceinline__ uint32_t fbits(float f) {
  union { float f; uint32_t u; } cv; cv.f = f; return cv.u;
}

// ---------------- fp32 -> bf16 convert: all 3 arrays in ONE launch ----------------
__global__ __launch_bounds__(256) void cvt3_kernel(
    const float* __restrict__ a, u16* __restrict__ da, int na4,
    const float* __restrict__ b, u16* __restrict__ db, int nb4,
    const float* __restrict__ c, u16* __restrict__ dc, int nc4) {
  int i = blockIdx.x * 256 + threadIdx.x;
  const float* s; u16* d;
  if (i < na4)             { s = a; d = da; }
  else if (i < na4 + nb4)  { s = b; d = db; i -= na4; }
  else if (i < na4 + nb4 + nc4) { s = c; d = dc; i -= na4 + nb4; }
  else return;
  const float4 f = ((const float4*)s)[i];
  u16x4 r;
  r[0] = f2bf(f.x); r[1] = f2bf(f.y); r[2] = f2bf(f.z); r[3] = f2bf(f.w);
  ((u16x4*)d)[i] = r;
}

// ---------------- QKV GEMM: C[8192,2304] = x @ qkv_w^T + b, scattered epilogue ----
// q (scaled by C1), k -> [bh][n][d] ; v -> transposed [bh][d][n]
__global__ __launch_bounds__(256) void gemm_qkv(const u16* __restrict__ A,
    const u16* __restrict__ B, const float* __restrict__ bias,
    u16* __restrict__ qg, u16* __restrict__ kg, u16* __restrict__ vtg) {
  __shared__ __align__(16) u16 at[128 * LSTR];
  __shared__ __align__(16) u16 bt[128 * LSTR];
  const int tid  = threadIdx.x;
  const int lane = tid & 63;
  const int w    = tid >> 6;
  const int quad = lane >> 4;
  const int col  = lane & 15;
  const int m0 = blockIdx.y * 128;
  const int n0 = blockIdx.x * 128;
  const int srow = tid >> 2;
  const int sch  = (tid & 3) * 8;
  const int wm = (w >> 1) * 64;
  const int wn = (w & 1) * 64;

  const f4v fz = {0.f, 0.f, 0.f, 0.f};
  f4v acc[4][4];
#pragma unroll
  for (int i = 0; i < 4; i++)
#pragma unroll
    for (int j = 0; j < 4; j++) acc[i][j] = fz;

  const u16* ap0 = A + (size_t)(m0 + srow) * NDIM + sch;
  const u16* ap1 = A + (size_t)(m0 + 64 + srow) * NDIM + sch;
  const u16* bp0 = B + (size_t)(n0 + srow) * NDIM + sch;
  const u16* bp1 = B + (size_t)(n0 + 64 + srow) * NDIM + sch;

  for (int k0 = 0; k0 < NDIM; k0 += 32) {
    const s8v va0 = *(const s8v*)(ap0 + k0);
    const s8v va1 = *(const s8v*)(ap1 + k0);
    const s8v vb0 = *(const s8v*)(bp0 + k0);
    const s8v vb1 = *(const s8v*)(bp1 + k0);
    __syncthreads();
    *(s8v*)(at + srow * LSTR + sch) = va0;
    *(s8v*)(at + (64 + srow) * LSTR + sch) = va1;
    *(s8v*)(bt + srow * LSTR + sch) = vb0;
    *(s8v*)(bt + (64 + srow) * LSTR + sch) = vb1;
    __syncthreads();
    s8v af[4], bf[4];
#pragma unroll
    for (int i = 0; i < 4; i++)
      af[i] = *(const s8v*)(at + (wm + i * 16 + col) * LSTR + quad * 8);
#pragma unroll
    for (int j = 0; j < 4; j++)
      bf[j] = *(const s8v*)(bt + (wn + j * 16 + col) * LSTR + quad * 8);
#pragma unroll
    for (int i = 0; i < 4; i++)
#pragma unroll
      for (int j = 0; j < 4; j++)
        acc[i][j] = __builtin_amdgcn_mfma_f32_16x16x32_bf16(af[i], bf[j], acc[i][j], 0, 0, 0);
  }

  const int wmg = m0 + wm;
  const int wng = n0 + wn;
  const int s = n0 / NDIM;   // 0=q 1=k 2=v, block-uniform (768 = 6*128)
#pragma unroll
  for (int j = 0; j < 4; j++) {
    const int c = wng + j * 16 + col;
    const float bv = bias[c];
    const int r = c - s * NDIM;
    const int h = r >> 6;
    const int d = r & 63;
#pragma unroll
    for (int i = 0; i < 4; i++) {
      const int mb = wmg + i * 16 + quad * 4;   // 4 consecutive rows (regs)
      const int bb = mb >> 12;
      const int n  = mb & 4095;
      const size_t hb = (size_t)(bb * NH + h);
      const f4v v = acc[i][j];
      if (s == 2) {
        u16x4 pk;
#pragma unroll
        for (int rg = 0; rg < 4; rg++) pk[rg] = f2bf(v[rg] + bv);
        *(u16x4*)(vtg + (hb * HD + d) * SEQ + n) = pk;   // transposed store
      } else if (s == 0) {
#pragma unroll
        for (int rg = 0; rg < 4; rg++)
          qg[(hb * SEQ + (size_t)(n + rg)) * HD + d] = f2bf((v[rg] + bv) * C1);
      } else {
#pragma unroll
        for (int rg = 0; rg < 4; rg++)
          kg[(hb * SEQ + (size_t)(n + rg)) * HD + d] = f2bf(v[rg] + bv);
      }
    }
  }
}

// ---------------- flash attention (LDS-staged K/V, fully conflict-free) ----------------
// K/V staged in [row][64+8] stride-72 panels: staging writes AND b128 frag
// reads are bank-conflict-free (see PSTR comment). Q frags in registers.
// P round-trips a wave-PRIVATE stride-72 panel (no barrier needed for it).
__global__ __launch_bounds__(256) void attn_kernel(const u16* __restrict__ qg,
    const u16* __restrict__ kg, const u16* __restrict__ vtg, u16* __restrict__ og) {
  __shared__ __align__(16) u16 kls[64 * PSTR];   // [key][64 d + 8 pad]
  __shared__ __align__(16) u16 vls[64 * PSTR];   // [d row][64 keys + 8 pad]
  __shared__ __align__(16) u16 pls[128 * PSTR];  // [q row][64 keys + 8 pad]

  const int tid  = threadIdx.x;
  const int lane = tid & 63;
  const int w    = tid >> 6;
  const int quad = lane >> 4;
  const int col  = lane & 15;
  // XCD swizzle: bh = blk % 24 -> all q-tiles of one (b,h) land on the same
  // XCD (blocks bh+24j: 24j % 8 == 0) -> K/V L2-resident per XCD.
  const int blk = blockIdx.x;
  const int bh  = blk % NBH;
  const int q0  = (blk / NBH) * 128;
  const size_t gbase = (size_t)bh * (SEQ * HD);
  const int wq = w * 32;           // this wave's q-column base

  // Q fragments in registers, once per block (R5-verified mapping)
  s8v qf[2][2];
#pragma unroll
  for (int s = 0; s < 2; s++)
#pragma unroll
    for (int qt = 0; qt < 2; qt++)
      qf[s][qt] = *(const s8v*)(qg + gbase +
          (size_t)(q0 + wq + qt * 16 + col) * HD + s * 32 + quad * 8);

  const f4v fz = {0.f, 0.f, 0.f, 0.f};
  f4v l4[2] = {fz, fz};
  f4v o[4][2];
#pragma unroll
  for (int dt = 0; dt < 4; dt++)
#pragma unroll
    for (int qt = 0; qt < 2; qt++) o[dt][qt] = fz;

  // staging: 8 lanes per row (row=tid>>3, chunk=(tid&7)*8), 2 passes of 32 rows
  const int srow8 = tid >> 3;        // 0..31
  const int sch8  = (tid & 7) * 8;   // 0..56
  const u16* kp = kg  + gbase + (size_t)srow8 * HD  + sch8;   // +(kb+32p)*HD
  const u16* vp = vtg + gbase + (size_t)srow8 * SEQ;          // +32p*SEQ +kb+sch8
  u16* const prow = pls + (wq + col) * PSTR;       // + qt*16*PSTR

  // prefetch iter 0 (coalesced 16B/lane)
  s8v kr0 = *(const s8v*)(kp);
  s8v kr1 = *(const s8v*)(kp + (size_t)32 * HD);
  s8v vr0 = *(const s8v*)(vp + sch8);
  s8v vr1 = *(const s8v*)(vp + (size_t)32 * SEQ + sch8);

  for (int kb = 0; kb < SEQ; kb += 64) {
    __syncthreads();
    *(s8v*)(kls + srow8 * PSTR + sch8) = kr0;
    *(s8v*)(kls + (32 + srow8) * PSTR + sch8) = kr1;
    *(s8v*)(vls + srow8 * PSTR + sch8) = vr0;
    *(s8v*)(vls + (32 + srow8) * PSTR + sch8) = vr1;
    __syncthreads();

    // prefetch next K/V tile; latency hides under this iter's compute
    if (kb + 64 < SEQ) {
      kr0 = *(const s8v*)(kp + (size_t)(kb + 64) * HD);
      kr1 = *(const s8v*)(kp + (size_t)(kb + 96) * HD);
      vr0 = *(const s8v*)(vp + kb + 64 + sch8);
      vr1 = *(const s8v*)(vp + (size_t)32 * SEQ + kb + 64 + sch8);
    }

    // St = K @ Q^T (C-layout: row=key, col=q), 2 K-steps over d
    f4v st[4][2];
#pragma unroll
    for (int kt = 0; kt < 4; kt++)
#pragma unroll
      for (int qt = 0; qt < 2; qt++) st[kt][qt] = fz;
#pragma unroll
    for (int s = 0; s < 2; s++) {
#pragma unroll
      for (int kt = 0; kt < 4; kt++) {
        const s8v ak = *(const s8v*)(kls + (kt * 16 + col) * PSTR + s * 32 + quad * 8);
#pragma unroll
        for (int qt = 0; qt < 2; qt++)
          st[kt][qt] = __builtin_amdgcn_mfma_f32_16x16x32_bf16(ak, qf[s][qt], st[kt][qt], 0, 0, 0);
      }
    }

    // p = exp2(st); per-lane l; pack bf16 (round-half-up + v_perm), b64 write
    // into the wave-private padded P panel: row = q, offset = key (0..63).
#pragma unroll
    for (int qt = 0; qt < 2; qt++) {
      u16* const pq = prow + qt * 16 * PSTR;
#pragma unroll
      for (int kt = 0; kt < 4; kt++) {
        f4v p;
#pragma unroll
        for (int rg = 0; rg < 4; rg++) p[rg] = ex2(st[kt][qt][rg]);
        l4[qt] += p;
        const uint32_t u0 = fbits(p[0]) + 0x8000u;
        const uint32_t u1 = fbits(p[1]) + 0x8000u;
        const uint32_t u2 = fbits(p[2]) + 0x8000u;
        const uint32_t u3 = fbits(p[3]) + 0x8000u;
        u32x2a wv;
        wv.x = __builtin_amdgcn_perm(u1, u0, 0x07060302u);
        wv.y = __builtin_amdgcn_perm(u3, u2, 0x07060302u);
        *(u32x2a*)(pq + kt * 16 + quad * 4) = wv;
      }
    }
    // compiler memory fence: P writes precede the B-frag reads below
    asm volatile("" ::: "memory");

    // O' += Vt @ Pt, 2 K-steps over keys
#pragma unroll
    for (int s = 0; s < 2; s++) {
      s8va bp[2];
#pragma unroll
      for (int qt = 0; qt < 2; qt++)
        bp[qt] = *(const s8va*)(prow + qt * 16 * PSTR + s * 32 + quad * 8);
#pragma unroll
      for (int dt = 0; dt < 4; dt++) {
        const s8v av = *(const s8v*)(vls + (dt * 16 + col) * PSTR + s * 32 + quad * 8);
#pragma unroll
        for (int qt = 0; qt < 2; qt++)
          o[dt][qt] = __builtin_amdgcn_mfma_f32_16x16x32_bf16(av, (s8v)bp[qt], o[dt][qt], 0, 0, 0);
      }
    }
    // fence: next iter's P writes (same addrs) must not hoist above these reads
    asm volatile("" ::: "memory");
  }

  // epilogue: reduce l across quads, O'[d][q]/l -> attn_out[b*4096+q][h*64+d]
  const int b = bh / NH;
  const int h = bh % NH;
#pragma unroll
  for (int qt = 0; qt < 2; qt++) {
    float l = l4[qt][0] + l4[qt][1] + l4[qt][2] + l4[qt][3];
    l += __shfl_xor(l, 16);
    l += __shfl_xor(l, 32);
    const float inv = 1.0f / l;
    const int qi = q0 + wq + qt * 16 + col;
    u16* rowp = og + (size_t)(b * SEQ + qi) * NDIM + h * HD;
#pragma unroll
    for (int dt = 0; dt < 4; dt++) {
      u16x4 pk;
#pragma unroll
      for (int rg = 0; rg < 4; rg++) pk[rg] = f2bf(o[dt][qt][rg] * inv);
      *(u16x4*)(rowp + dt * 16 + quad * 4) = pk;
    }
  }
}

// ---------------- proj GEMM: out[8192,768] = attn @ proj_w^T + b (fp32 out) ----
__global__ __launch_bounds__(256) void gemm_proj(const u16* __restrict__ A,
    const u16* __restrict__ B, const float* __restrict__ bias, float* __restrict__ out) {
  __shared__ __align__(16) u16 at[128 * LSTR];
  __shared__ __align__(16) u16 bt[128 * LSTR];
  const int tid  = threadIdx.x;
  const int lane = tid & 63;
  const int w    = tid >> 6;
  const int quad = lane >> 4;
  const int col  = lane & 15;
  const int m0 = blockIdx.y * 128;
  const int n0 = blockIdx.x * 128;
  const int srow = tid >> 2;
  const int sch  = (tid & 3) * 8;
  const int wm = (w >> 1) * 64;
  const int wn = (w & 1) * 64;

  const f4v fz = {0.f, 0.f, 0.f, 0.f};
  f4v acc[4][4];
#pragma unroll
  for (int i = 0; i < 4; i++)
#pragma unroll
    for (int j = 0; j < 4; j++) acc[i][j] = fz;

  const u16* ap0 = A + (size_t)(m0 + srow) * NDIM + sch;
  const u16* ap1 = A + (size_t)(m0 + 64 + srow) * NDIM + sch;
  const u16* bp0 = B + (size_t)(n0 + srow) * NDIM + sch;
  const u16* bp1 = B + (size_t)(n0 + 64 + srow) * NDIM + sch;

  for (int k0 = 0; k0 < NDIM; k0 += 32) {
    const s8v va0 = *(const s8v*)(ap0 + k0);
    const s8v va1 = *(const s8v*)(ap1 + k0);
    const s8v vb0 = *(const s8v*)(bp0 + k0);
    const s8v vb1 = *(const s8v*)(bp1 + k0);
    __syncthreads();
    *(s8v*)(at + srow * LSTR + sch) = va0;
    *(s8v*)(at + (64 + srow) * LSTR + sch) = va1;
    *(s8v*)(bt + srow * LSTR + sch) = vb0;
    *(s8v*)(bt + (64 + srow) * LSTR + sch) = vb1;
    __syncthreads();
    s8v af[4], bf[4];
#pragma unroll
    for (int i = 0; i < 4; i++)
      af[i] = *(const s8v*)(at + (wm + i * 16 + col) * LSTR + quad * 8);
#pragma unroll
    for (int j = 0; j < 4; j++)
      bf[j] = *(const s8v*)(bt + (wn + j * 16 + col) * LSTR + quad * 8);
#pragma unroll
    for (int i = 0; i < 4; i++)
#pragma unroll
      for (int j = 0; j < 4; j++)
        acc[i][j] = __builtin_amdgcn_mfma_f32_16x16x32_bf16(af[i], bf[j], acc[i][j], 0, 0, 0);
  }

  const int wmg = m0 + wm;
  const int wng = n0 + wn;
#pragma unroll
  for (int j = 0; j < 4; j++) {
    const int c = wng + j * 16 + col;
    const float bv = bias[c];
#pragma unroll
    for (int i = 0; i < 4; i++) {
#pragma unroll
      for (int rg = 0; rg < 4; rg++)
        out[(size_t)(wmg + i * 16 + quad * 4 + rg) * NDIM + c] = acc[i][j][rg] + bv;
    }
  }
}

// ---------------- launch ----------------
extern "C" void kernel_launch(void* const* d_in, const int* in_sizes, int n_in,
                              void* d_out, int out_size, void* d_ws, size_t ws_size,
                              hipStream_t stream) {
  const float* x      = (const float*)d_in[0];
  const float* qkv_w  = (const float*)d_in[1];
  const float* qkv_b  = (const float*)d_in[2];
  const float* proj_w = (const float*)d_in[3];
  const float* proj_b = (const float*)d_in[4];
  float* out = (float*)d_out;

  u16* ws   = (u16*)d_ws;
  u16* x_bf = ws;                              // 8192*768
  u16* wq   = x_bf + (size_t)MTOT * NDIM;      // 2304*768
  u16* wp   = wq + (size_t)3 * NDIM * NDIM;    // 768*768
  u16* q_bf = wp + (size_t)NDIM * NDIM;        // 24*4096*64 each
  u16* k_bf = q_bf + (size_t)NBH * SEQ * HD;
  u16* vt   = k_bf + (size_t)NBH * SEQ * HD;
  u16* a_bf = vt + (size_t)NBH * SEQ * HD;     // 8192*768

  const int nx = MTOT * NDIM / 4, nw1 = 3 * NDIM * NDIM / 4, nw2 = NDIM * NDIM / 4;
  const int ntot = nx + nw1 + nw2;
  cvt3_kernel<<<(ntot + 255) / 256, 256, 0, stream>>>(x, x_bf, nx, qkv_w, wq, nw1,
                                                      proj_w, wp, nw2);

  gemm_qkv<<<dim3(18, 64), 256, 0, stream>>>(x_bf, wq, qkv_b, q_bf, k_bf, vt);
  attn_kernel<<<768, 256, 0, stream>>>(q_bf, k_bf, vt, a_bf);
  gemm_proj<<<dim3(6, 64), 256, 0, stream>>>(a_bf, wp, proj_b, out);
}